// Round 3
// baseline (58.919 us; speedup 1.0000x reference)
//
#include <hip/hip_runtime.h>
#include <math.h>

namespace {

constexpr int kB = 16, kT = 50, kH = 96, kW = 96, kA = 5;
constexpr int kCH = 15;                         // 7 + 8 channels per anchor
constexpr int kPlane = kH * kW;                 // 9216
constexpr int kBlk = 256;
constexpr int kBlocksPerImg = kA * kPlane / kBlk;  // 180
constexpr int kBlkPerPlane = kPlane / kBlk;        // 36 (exact)
constexpr float kObjSq = 100.0f;                   // OBJ^2

// d_ws layout: [0,12800) float4 rec[800] {x0,x1,y0,y1}; [12800,16000) float cthr[800]
constexpr size_t kOffC = 12800;

__device__ __forceinline__ float fast_sigmoid(float v) {
  return __builtin_amdgcn_rcpf(1.0f + __expf(-v));
}

// Kernel P <<<16, 64>>>: block b = image b (one wave).
//  - per-target: validity prefix, best anchor, scatter idx, corner record
//  - writes rec/cthr to global for the hot kernel
//  - per-target exact IoU -> nCorrect; unique-owner cells: full owner loss
//    MINUS a bit-matched replica of the noobj term the hot kernel will add
//  - accumulates into d_out (pre-zeroed by hipMemsetAsync)
__global__ __launch_bounds__(64) void prep_kernel(
    const float* __restrict__ out, const float* __restrict__ tgt,
    const float* __restrict__ anc, float4* __restrict__ rec,
    float* __restrict__ cthr, float* __restrict__ d_out) {
  __shared__ float s_x0[kT], s_x1[kT], s_y0[kT], s_y1[kT], s_c[kT];
  __shared__ int s_idx[kT];

  const int b = blockIdx.x, t = threadIdx.x;
  const float* tp = tgt + (b * kT + (t < kT ? t : 0)) * 7;
  const float c0 = tp[0], g1 = tp[1], g2 = tp[2], g3 = tp[3], g4 = tp[4];
  const float e5 = tp[5], e6 = tp[6];
  unsigned long long nzm = __ballot((t < kT) && (g1 != 0.0f));
  bool valid = false;
  int idx = -1, bn = 0, gi = 0, gj = 0;
  float gx = 0, gy = 0, gw = 0, gl = 0;
  if (t < kT) {
    valid = ((~nzm) & ((1ull << (t + 1)) - 1ull)) == 0ull;  // cumprod prefix
    gx = g1 * kW; gy = g2 * kH; gw = g3 * kW; gl = g4 * kH;
    float best = -1.0f;
    for (int a = 0; a < kA; ++a) {
      float aw = anc[2 * a], ah = anc[2 * a + 1];
      float inter = fminf(gw, aw) * fminf(gl, ah);
      float iou = inter / (gw * gl + aw * ah - inter);
      if (iou > best) { best = iou; bn = a; }  // argmax (first max wins)
    }
    gi = min(max((int)gx, 0), kW - 1);
    gj = min(max((int)gy, 0), kH - 1);
    idx = ((b * kA + bn) * kH + gj) * kW + gi;
    float4 r; float c;
    if (valid) {
      r = make_float4(gx - gw * 0.5f, gx + gw * 0.5f,
                      gy - gl * 0.5f, gy + gl * 0.5f);
      c = 0.375f * (gw * gl);
    } else {  // sentinel: inter -> 0, margin -> -huge
      r = make_float4(1e30f, -1e30f, 1e30f, -1e30f);
      c = 1e30f;
    }
    rec[b * kT + t] = r;
    cthr[b * kT + t] = c;
    s_x0[t] = r.x; s_x1[t] = r.y; s_y0[t] = r.z; s_y1[t] = r.w; s_c[t] = c;
    s_idx[t] = valid ? idx : -1;
  }
  __syncthreads();

  float loss = 0.0f;
  int ncorr = 0;
  if (valid) {
    bool owner = true;  // last valid t with this idx wins (in-order scatter)
    for (int t2 = 0; t2 < kT; ++t2)
      owner &= !((t2 > t) && (s_idx[t2] == idx));

    const float* p = out + ((size_t)(b * kA + bn) * kCH) * kPlane + gj * kW + gi;
    const float xr = p[0], yr = p[kPlane], wr = p[2 * kPlane], lr = p[3 * kPlane];
    const float aw = anc[2 * bn], ah = anc[2 * bn + 1];
    const float x = 1.0f / (1.0f + expf(-xr));
    const float y = 1.0f / (1.0f + expf(-yr));
    const float px = x + (float)gi, py = y + (float)gj;
    const float pw = expf(wr) * aw, pl = expf(lr) * ah;
    // exact IoU (reference formulation) -> tconf / nCorrect
    float mx = fminf(px - pw * 0.5f, gx - gw * 0.5f);
    float Mx = fmaxf(px + pw * 0.5f, gx + gw * 0.5f);
    float my = fminf(py - pl * 0.5f, gy - gl * 0.5f);
    float My = fmaxf(py + pl * 0.5f, gy + gl * 0.5f);
    float cw = pw + gw - (Mx - mx);
    float ch = pl + gl - (My - my);
    float inter = (cw > 0.0f && ch > 0.0f) ? cw * ch : 0.0f;
    float iou = inter / (pw * pl + gw * gl - inter);
    ncorr = (iou > 0.5f) ? 1 : 0;

    if (owner) {
      const float imv = p[4 * kPlane], rev = p[5 * kPlane], cr = p[6 * kPlane];
      float tx = gx - (float)gi, ty = gy - (float)gj;
      float tw = logf(gw / aw), tl = logf(gl / ah);
      float conf = 1.0f / (1.0f + expf(-cr));
      float dx = x - tx, dy = y - ty, dw = wr - tw, dl = lr - tl;
      float di = imv - e5, dr = rev - e6, dc = conf - iou;
      loss = dx * dx + dy * dy + dw * dw + dl * dl + di * di + dr * dr +
             kObjSq * dc * dc;
      // cross-entropy over 8 class logits
      const float cv0 = p[7 * kPlane],  cv1 = p[8 * kPlane];
      const float cv2 = p[9 * kPlane],  cv3 = p[10 * kPlane];
      const float cv4 = p[11 * kPlane], cv5 = p[12 * kPlane];
      const float cv6 = p[13 * kPlane], cv7 = p[14 * kPlane];
      float m = fmaxf(fmaxf(fmaxf(cv0, cv1), fmaxf(cv2, cv3)),
                      fmaxf(fmaxf(cv4, cv5), fmaxf(cv6, cv7)));
      float s = expf(cv0 - m) + expf(cv1 - m) + expf(cv2 - m) + expf(cv3 - m) +
                expf(cv4 - m) + expf(cv5 - m) + expf(cv6 - m) + expf(cv7 - m);
      float lse = m + logf(s);
      int ci = min(max((int)c0, 0), 7);
      float csel = cv0;
      csel = (ci == 1) ? cv1 : csel;
      csel = (ci == 2) ? cv2 : csel;
      csel = (ci == 3) ? cv3 : csel;
      csel = (ci == 4) ? cv4 : csel;
      csel = (ci == 5) ? cv5 : csel;
      csel = (ci == 6) ? cv6 : csel;
      csel = (ci == 7) ? cv7 : csel;
      loss += lse - csel;

      // subtract the noobj term the hot kernel will add at this cell
      // (replicated with the SAME fast-math path as noobj_kernel)
      float pxf = fast_sigmoid(xr) + (float)gi;
      float pyf = fast_sigmoid(yr) + (float)gj;
      float pwf = __expf(wr) * aw, plf = __expf(lr) * ah;
      float px0 = pxf - pwf * 0.5f, px1 = pxf + pwf * 0.5f;
      float py0 = pyf - plf * 0.5f, py1 = pyf + plf * 0.5f;
      float pthr = 0.375f * (pwf * plf);
      float conff = fast_sigmoid(cr);
      float hh = -1e30f;
      for (int t2 = 0; t2 < kT; ++t2) {
        float cw2 = fminf(px1, s_x1[t2]) - fmaxf(px0, s_x0[t2]);
        float ch2 = fminf(py1, s_y1[t2]) - fmaxf(py0, s_y0[t2]);
        hh = fmaxf(hh, fmaxf(cw2, 0.0f) * fmaxf(ch2, 0.0f) - s_c[t2]);
      }
      if (!(hh > pthr)) loss -= conff * conff;
    }
  }
  for (int off = 32; off > 0; off >>= 1) {
    loss += __shfl_down(loss, off, 64);
    ncorr += __shfl_down(ncorr, off, 64);
  }
  int ngt = __popcll(__ballot(valid));
  if (t == 0) {
    atomicAdd(d_out + 0, loss);
    atomicAdd(d_out + 1, (float)ncorr);
    atomicAdd(d_out + 2, (float)ngt);
  }
}

// Kernel B (hot): noobj conf loss for EVERY cell; box table read via the
// scalar pipe (wave-uniform address -> s_load_dwordx4), zero LDS in the loop.
//   maxiou > 0.6  <=>  max_t(inter_t - 0.375*garea_t) > 0.375*parea
__global__ __launch_bounds__(kBlk) void noobj_kernel(
    const float* __restrict__ out, const float* __restrict__ anc,
    const float4* __restrict__ rec, const float* __restrict__ cthr,
    float* __restrict__ d_out) {
  __shared__ float s_red[kBlk / 64];

  const int tid = threadIdx.x;
  const int b = blockIdx.x / kBlocksPerImg;
  const int blk = blockIdx.x % kBlocksPerImg;
  const int a = blk / kBlkPerPlane;                   // block-uniform
  const int rem = (blk % kBlkPerPlane) * kBlk + tid;  // 0..9215
  const int j = rem / kW, i = rem % kW;

  const float* p = out + ((size_t)(b * kA + a) * kCH) * kPlane + rem;
  const float xr = p[0];
  const float yr = p[kPlane];
  const float w = p[2 * kPlane];
  const float l = p[3 * kPlane];
  const float cr = p[6 * kPlane];

  const float aw = anc[2 * a], ah = anc[2 * a + 1];  // uniform -> s_load
  const float px = fast_sigmoid(xr) + (float)i;
  const float py = fast_sigmoid(yr) + (float)j;
  const float pw = __expf(w) * aw;
  const float pl = __expf(l) * ah;
  const float px0 = px - pw * 0.5f, px1 = px + pw * 0.5f;
  const float py0 = py - pl * 0.5f, py1 = py + pl * 0.5f;
  const float pthr = 0.375f * (pw * pl);
  const float conf = fast_sigmoid(cr);

  // force-uniform base so the box table goes through the scalar pipe
  const int rbase = __builtin_amdgcn_readfirstlane(b * kT);
  const float4* rb = rec + rbase;
  const float* cb = cthr + rbase;

  float hh = -1e30f;
#pragma unroll
  for (int t = 0; t < kT; ++t) {
    const float4 bx = rb[t];   // s_load_dwordx4 (uniform)
    const float c = cb[t];     // s_load_dword (uniform)
    float cw = fminf(px1, bx.y) - fmaxf(px0, bx.x);
    float ch = fminf(py1, bx.w) - fmaxf(py0, bx.z);
    hh = fmaxf(hh, fmaxf(cw, 0.0f) * fmaxf(ch, 0.0f) - c);
  }
  float loss = (hh > pthr) ? 0.0f : conf * conf;

  for (int off = 32; off > 0; off >>= 1) loss += __shfl_down(loss, off, 64);
  if ((tid & 63) == 0) s_red[tid >> 6] = loss;
  __syncthreads();
  if (tid == 0) {
    float L = s_red[0] + s_red[1] + s_red[2] + s_red[3];
    atomicAdd(d_out, L);
  }
}

}  // namespace

extern "C" void kernel_launch(void* const* d_in, const int* in_sizes, int n_in,
                              void* d_out, int out_size, void* d_ws,
                              size_t ws_size, hipStream_t stream) {
  const float* output = (const float*)d_in[0];
  const float* target = (const float*)d_in[1];
  const float* anchors = (const float*)d_in[2];
  float* outp = (float*)d_out;
  char* ws = (char*)d_ws;
  float4* rec = (float4*)ws;
  float* cthr = (float*)(ws + kOffC);

  hipMemsetAsync(d_out, 0, 3 * sizeof(float), stream);
  prep_kernel<<<kB, 64, 0, stream>>>(output, target, anchors, rec, cthr, outp);
  noobj_kernel<<<kB * kBlocksPerImg, kBlk, 0, stream>>>(output, anchors, rec,
                                                        cthr, outp);
}

// Round 4
// 26.037 us; speedup vs baseline: 2.2629x; 2.2629x over previous
//
#include <hip/hip_runtime.h>
#include <math.h>

namespace {

constexpr int kB = 16, kT = 50, kH = 96, kW = 96, kA = 5;
constexpr int kCH = 15;                    // 7 + 8 channels per anchor
constexpr int kPlane = kH * kW;            // 9216
constexpr int kCellsPerBlk = 1024;         // 256 threads * 4 cells
constexpr int kBlkPerPlane = kPlane / kCellsPerBlk;       // 9 (exact)
constexpr int kNoobjBlocks = kB * kA * kBlkPerPlane;      // 720
constexpr float kObjSq = 100.0f;           // OBJ^2

__device__ __forceinline__ float fast_sigmoid(float v) {
  return __builtin_amdgcn_rcpf(1.0f + __expf(-v));
}

// Per-target record; must be executed by a full wave (lanes 0..63),
// lane = target id. Arithmetic here is the single source of truth for the
// box table -- owner blocks and noobj blocks both call this, so the
// owner-side replica of the noobj term matches bit-exactly.
__device__ __forceinline__ void make_rec(
    const float* __restrict__ tgt, const float* __restrict__ anc, int b,
    int lane, float4& r, float& c, int& vidx, bool& valid, float& gx,
    float& gy, float& gw, float& gl, int& bn, int& gi, int& gj, float& c0,
    float& e5, float& e6) {
  const float* tp = tgt + (b * kT + (lane < kT ? lane : 0)) * 7;
  c0 = tp[0];
  const float g1 = tp[1], g2 = tp[2], g3 = tp[3], g4 = tp[4];
  e5 = tp[5];
  e6 = tp[6];
  unsigned long long nzm = __ballot((lane < kT) && (g1 != 0.0f));
  valid = false;
  vidx = -1;
  bn = 0;
  gi = 0;
  gj = 0;
  gx = g1 * kW; gy = g2 * kH; gw = g3 * kW; gl = g4 * kH;
  r = make_float4(1e30f, -1e30f, 1e30f, -1e30f);  // sentinel
  c = 1e30f;
  if (lane < kT) {
    valid = ((~nzm) & ((1ull << (lane + 1)) - 1ull)) == 0ull;  // cumprod
    float best = -1.0f;
    for (int a = 0; a < kA; ++a) {
      float aw = anc[2 * a], ah = anc[2 * a + 1];
      float inter = fminf(gw, aw) * fminf(gl, ah);
      float iou = inter / (gw * gl + aw * ah - inter);
      if (iou > best) { best = iou; bn = a; }  // argmax (first max wins)
    }
    gi = min(max((int)gx, 0), kW - 1);
    gj = min(max((int)gy, 0), kH - 1);
    int idx = ((b * kA + bn) * kH + gj) * kW + gi;
    vidx = valid ? idx : -1;
    if (valid) {
      r = make_float4(gx - gw * 0.5f, gx + gw * 0.5f, gy - gl * 0.5f,
                      gy + gl * 0.5f);
      c = 0.375f * (gw * gl);
    }
  }
}

// One fused kernel. Blocks [0,16): per-target/owner work for image b=blk
// (one wave; no barriers). Blocks [16,736): noobj loss, 4 cells/thread.
__global__ __launch_bounds__(256) void fused_kernel(
    const float* __restrict__ out, const float* __restrict__ tgt,
    const float* __restrict__ anc, float* __restrict__ d_out) {
  __shared__ float4 s_box[kT];
  __shared__ float s_c[kT];
  __shared__ float s_red[4];

  const int blk = blockIdx.x;
  const int tid = threadIdx.x;

  if (blk < kB) {  // ---------------- owner / per-target block ------------
    if (tid >= 64) return;  // one wave; no __syncthreads on this path
    const int b = blk, t = tid;
    float4 r; float c; int vidx; bool valid;
    float gx, gy, gw, gl, c0, e5, e6; int bn, gi, gj;
    make_rec(tgt, anc, b, t, r, c, vidx, valid, gx, gy, gw, gl, bn, gi, gj,
             c0, e5, e6);
    const int ngt = __popcll(__ballot(valid));

    float loss = 0.0f;
    int ncorr = 0;
    if (valid) {
      bool owner = true;  // last valid t with this idx wins
      for (int t2 = 0; t2 < kT; ++t2) {
        int v2 = __shfl(vidx, t2);
        owner &= !((t2 > t) && (v2 == vidx));
      }
      const float* p =
          out + ((size_t)(b * kA + bn) * kCH) * kPlane + gj * kW + gi;
      const float xr = p[0], yr = p[kPlane];
      const float wr = p[2 * kPlane], lr = p[3 * kPlane];
      const float aw = anc[2 * bn], ah = anc[2 * bn + 1];
      const float x = 1.0f / (1.0f + expf(-xr));
      const float y = 1.0f / (1.0f + expf(-yr));
      const float px = x + (float)gi, py = y + (float)gj;
      const float pw = expf(wr) * aw, pl = expf(lr) * ah;
      // exact IoU (reference formulation) -> tconf / nCorrect
      float mx = fminf(px - pw * 0.5f, gx - gw * 0.5f);
      float Mx = fmaxf(px + pw * 0.5f, gx + gw * 0.5f);
      float my = fminf(py - pl * 0.5f, gy - gl * 0.5f);
      float My = fmaxf(py + pl * 0.5f, gy + gl * 0.5f);
      float cw = pw + gw - (Mx - mx);
      float ch = pl + gl - (My - my);
      float inter = (cw > 0.0f && ch > 0.0f) ? cw * ch : 0.0f;
      float iou = inter / (pw * pl + gw * gl - inter);
      ncorr = (iou > 0.5f) ? 1 : 0;

      if (owner) {
        const float imv = p[4 * kPlane], rev = p[5 * kPlane];
        const float cr = p[6 * kPlane];
        float tx = gx - (float)gi, ty = gy - (float)gj;
        float tw = logf(gw / aw), tl = logf(gl / ah);
        float conf = 1.0f / (1.0f + expf(-cr));
        float dx = x - tx, dy = y - ty, dw = wr - tw, dl = lr - tl;
        float di = imv - e5, dr = rev - e6, dc = conf - iou;
        loss = dx * dx + dy * dy + dw * dw + dl * dl + di * di + dr * dr +
               kObjSq * dc * dc;
        // cross-entropy over 8 class logits
        const float cv0 = p[7 * kPlane],  cv1 = p[8 * kPlane];
        const float cv2 = p[9 * kPlane],  cv3 = p[10 * kPlane];
        const float cv4 = p[11 * kPlane], cv5 = p[12 * kPlane];
        const float cv6 = p[13 * kPlane], cv7 = p[14 * kPlane];
        float m = fmaxf(fmaxf(fmaxf(cv0, cv1), fmaxf(cv2, cv3)),
                        fmaxf(fmaxf(cv4, cv5), fmaxf(cv6, cv7)));
        float s = expf(cv0 - m) + expf(cv1 - m) + expf(cv2 - m) +
                  expf(cv3 - m) + expf(cv4 - m) + expf(cv5 - m) +
                  expf(cv6 - m) + expf(cv7 - m);
        float lse = m + logf(s);
        int ci = min(max((int)c0, 0), 7);
        float csel = cv0;
        csel = (ci == 1) ? cv1 : csel;
        csel = (ci == 2) ? cv2 : csel;
        csel = (ci == 3) ? cv3 : csel;
        csel = (ci == 4) ? cv4 : csel;
        csel = (ci == 5) ? cv5 : csel;
        csel = (ci == 6) ? cv6 : csel;
        csel = (ci == 7) ? cv7 : csel;
        loss += lse - csel;

        // subtract the noobj term the noobj blocks add at this cell,
        // replicated with the SAME fast-math ops in the SAME order
        float pxf = fast_sigmoid(xr) + (float)gi;
        float pyf = fast_sigmoid(yr) + (float)gj;
        float pwf = __expf(wr) * aw, plf = __expf(lr) * ah;
        float px0 = pxf - pwf * 0.5f, px1 = pxf + pwf * 0.5f;
        float py0 = pyf - plf * 0.5f, py1 = pyf + plf * 0.5f;
        float pthr = 0.375f * (pwf * plf);
        float conff = fast_sigmoid(cr);
        float hh = -1e30f;
        for (int t2 = 0; t2 < kT; ++t2) {
          float x0 = __shfl(r.x, t2), x1 = __shfl(r.y, t2);
          float y0 = __shfl(r.z, t2), y1 = __shfl(r.w, t2);
          float cc = __shfl(c, t2);
          float cw2 = fminf(px1, x1) - fmaxf(px0, x0);
          float ch2 = fminf(py1, y1) - fmaxf(py0, y0);
          hh = fmaxf(hh, fmaxf(cw2, 0.0f) * fmaxf(ch2, 0.0f) - cc);
        }
        if (!(hh > pthr)) loss -= conff * conff;
      }
    }
    for (int off = 32; off > 0; off >>= 1) {
      loss += __shfl_down(loss, off, 64);
      ncorr += __shfl_down(ncorr, off, 64);
    }
    if (t == 0) {
      atomicAdd(d_out + 0, loss);
      atomicAdd(d_out + 1, (float)ncorr);
      atomicAdd(d_out + 2, (float)ngt);
    }
    return;
  }

  // ---------------- noobj block: 4 consecutive cells per thread ----------
  const int nb = blk - kB;                 // 0..719
  const int plane = nb / kBlkPerPlane;     // b*5 + a
  const int b = plane / kA, a = plane % kA;
  const int base = (nb % kBlkPerPlane) * kCellsPerBlk;

  if (tid < 64) {  // wave 0 builds the box table
    float4 r; float c; int vidx; bool valid;
    float gx, gy, gw, gl, c0, e5, e6; int bn, gi, gj;
    make_rec(tgt, anc, b, tid, r, c, vidx, valid, gx, gy, gw, gl, bn, gi, gj,
             c0, e5, e6);
    if (tid < kT) { s_box[tid] = r; s_c[tid] = c; }
  }
  __syncthreads();

  const int cell0 = base + 4 * tid;        // multiple of 4; 96 % 4 == 0 =>
  const int j = cell0 / kW;                // the 4 cells share one row
  const int i0 = cell0 - j * kW;

  const float* pb = out + ((size_t)plane * kCH) * kPlane + cell0;
  const float4 xv = *(const float4*)(pb);
  const float4 yv = *(const float4*)(pb + kPlane);
  const float4 wv = *(const float4*)(pb + 2 * kPlane);
  const float4 lv = *(const float4*)(pb + 3 * kPlane);
  const float4 cv = *(const float4*)(pb + 6 * kPlane);
  const float aw = anc[2 * a], ah = anc[2 * a + 1];

  const float xs[4] = {xv.x, xv.y, xv.z, xv.w};
  const float ys[4] = {yv.x, yv.y, yv.z, yv.w};
  const float wss[4] = {wv.x, wv.y, wv.z, wv.w};
  const float ls[4] = {lv.x, lv.y, lv.z, lv.w};
  const float crs[4] = {cv.x, cv.y, cv.z, cv.w};

  float px0[4], px1[4], py0[4], py1[4], pthr[4], conf[4], hh[4];
#pragma unroll
  for (int e = 0; e < 4; ++e) {
    float px = fast_sigmoid(xs[e]) + (float)(i0 + e);
    float py = fast_sigmoid(ys[e]) + (float)j;
    float pw = __expf(wss[e]) * aw;
    float pl = __expf(ls[e]) * ah;
    px0[e] = px - pw * 0.5f; px1[e] = px + pw * 0.5f;
    py0[e] = py - pl * 0.5f; py1[e] = py + pl * 0.5f;
    pthr[e] = 0.375f * (pw * pl);
    conf[e] = fast_sigmoid(crs[e]);
    hh[e] = -1e30f;
  }

#pragma unroll 10
  for (int t = 0; t < kT; ++t) {
    const float4 bx = s_box[t];
    const float c = s_c[t];
#pragma unroll
    for (int e = 0; e < 4; ++e) {
      float cw = fminf(px1[e], bx.y) - fmaxf(px0[e], bx.x);
      float ch = fminf(py1[e], bx.w) - fmaxf(py0[e], bx.z);
      hh[e] = fmaxf(hh[e], fmaxf(cw, 0.0f) * fmaxf(ch, 0.0f) - c);
    }
  }

  float loss = 0.0f;
#pragma unroll
  for (int e = 0; e < 4; ++e)
    loss += (hh[e] > pthr[e]) ? 0.0f : conf[e] * conf[e];

  for (int off = 32; off > 0; off >>= 1) loss += __shfl_down(loss, off, 64);
  if ((tid & 63) == 0) s_red[tid >> 6] = loss;
  __syncthreads();
  if (tid == 0)
    atomicAdd(d_out, s_red[0] + s_red[1] + s_red[2] + s_red[3]);
}

}  // namespace

extern "C" void kernel_launch(void* const* d_in, const int* in_sizes, int n_in,
                              void* d_out, int out_size, void* d_ws,
                              size_t ws_size, hipStream_t stream) {
  const float* output = (const float*)d_in[0];
  const float* target = (const float*)d_in[1];
  const float* anchors = (const float*)d_in[2];
  float* outp = (float*)d_out;

  hipMemsetAsync(d_out, 0, 3 * sizeof(float), stream);
  fused_kernel<<<kB + kNoobjBlocks, 256, 0, stream>>>(output, target, anchors,
                                                      outp);
}